// Round 1
// baseline (95.967 us; speedup 1.0000x reference)
//
#include <hip/hip_runtime.h>
#include <math.h>

// ASD (average symmetric surface distance) between two 16384x3 fp32 point sets.
// Compute-bound fp32 VALU problem (no fp32 MFMA on CDNA4; bf16 MFMA numerically
// insufficient: 8 mantissa bits on coords ~128 -> ~0.5 abs error >> 0.057 thresh).
//
// Strategy: d2(q,r) = q2 + (r2 - 2 q.r); hoist q2 out of the min.
// Inner loop per ref: 1 broadcast ds_read_b128 (x,y,z,r2) + 5 VALU per query.
// Grid: 2 dirs x 8 ref-chunks x 32 query-blocks = 512 blocks of 256 threads
// (2 blocks/CU -> 2 waves/SIMD). Partial mins to ws[8][32768]; second kernel
// reduces: min over chunks, sqrt(max(m+q2,0)), tree-sum, /32768.

#define NPTS    16384
#define THREADS 256
#define QPT     2                    // queries per thread
#define QBLK    (THREADS * QPT)      // 512 queries per block
#define NQB     (NPTS / QBLK)        // 32 query-blocks per direction
#define NCHUNK  8
#define CHUNK   (NPTS / NCHUNK)      // 2048 refs per chunk

__global__ __launch_bounds__(THREADS) void asd_min_kernel(
    const float* __restrict__ real_pts,
    const float* __restrict__ pred_pts,
    float* __restrict__ ws)
{
    const int bid   = blockIdx.x;
    const int dir   = bid >> 8;          // 256 blocks per direction
    const int rem   = bid & 255;
    const int chunk = rem >> 5;          // 8 chunks
    const int qb    = rem & 31;          // 32 query-blocks

    // dir 0: pred -> real ; dir 1: real -> pred
    const float* __restrict__ qpts = (dir == 0) ? pred_pts : real_pts;
    const float* __restrict__ rpts = (dir == 0) ? real_pts : pred_pts;

    __shared__ float4 sref[CHUNK];       // {x, y, z, x^2+y^2+z^2} per ref: 32 KB

    const int tid = threadIdx.x;

    // Stage ref chunk into LDS (one-time; data is L2-resident and tiny).
    const int rbase = chunk * CHUNK;
    for (int i = tid; i < CHUNK; i += THREADS) {
        const float rx = rpts[(rbase + i) * 3 + 0];
        const float ry = rpts[(rbase + i) * 3 + 1];
        const float rz = rpts[(rbase + i) * 3 + 2];
        sref[i] = make_float4(rx, ry, rz, fmaf(rx, rx, fmaf(ry, ry, rz * rz)));
    }

    // Load this thread's queries into registers.
    float qx[QPT], qy[QPT], qz[QPT], q2[QPT], m[QPT];
    const int q0 = qb * QBLK + tid;
#pragma unroll
    for (int k = 0; k < QPT; ++k) {
        const int qi = q0 + k * THREADS;
        qx[k] = qpts[qi * 3 + 0];
        qy[k] = qpts[qi * 3 + 1];
        qz[k] = qpts[qi * 3 + 2];
        q2[k] = fmaf(qx[k], qx[k], fmaf(qy[k], qy[k], qz[k] * qz[k]));
        m[k]  = INFINITY;                // track min over r of (r2 - 2 q.r)
    }

    __syncthreads();

#pragma unroll 4
    for (int r = 0; r < CHUNK; ++r) {
        const float4 rv = sref[r];       // broadcast read, conflict-free
#pragma unroll
        for (int k = 0; k < QPT; ++k) {
            float s = qx[k] * rv.x;
            s = fmaf(qy[k], rv.y, s);
            s = fmaf(qz[k], rv.z, s);
            const float d = fmaf(-2.0f, s, rv.w);   // r2 - 2 q.r
            m[k] = fminf(m[k], d);
        }
    }

    // Partial result for this (chunk, query): d2 - 0 (add q2 back now).
#pragma unroll
    for (int k = 0; k < QPT; ++k) {
        const int qi = q0 + k * THREADS;
        ws[chunk * (2 * NPTS) + dir * NPTS + qi] = m[k] + q2[k];
    }
}

__global__ __launch_bounds__(1024) void asd_reduce_kernel(
    const float* __restrict__ ws, float* __restrict__ out)
{
    const int tid = threadIdx.x;
    float s = 0.0f;

    for (int q = tid; q < 2 * NPTS; q += 1024) {
        float m = INFINITY;
#pragma unroll
        for (int c = 0; c < NCHUNK; ++c)
            m = fminf(m, ws[c * (2 * NPTS) + q]);
        s += sqrtf(fmaxf(m, 0.0f));      // numerical floor, matches reference
    }

    // Block reduction: wave64 shuffle then LDS across 16 waves.
    __shared__ float red[16];
#pragma unroll
    for (int off = 32; off > 0; off >>= 1)
        s += __shfl_down(s, off, 64);
    const int wave = tid >> 6;
    const int lane = tid & 63;
    if (lane == 0) red[wave] = s;
    __syncthreads();
    if (tid < 16) {
        float v = red[tid];
#pragma unroll
        for (int off = 8; off > 0; off >>= 1)
            v += __shfl_down(v, off, 16);
        if (tid == 0) out[0] = v / (float)(2 * NPTS);
    }
}

extern "C" void kernel_launch(void* const* d_in, const int* in_sizes, int n_in,
                              void* d_out, int out_size, void* d_ws, size_t ws_size,
                              hipStream_t stream)
{
    const float* real_pts = (const float*)d_in[0];
    const float* pred_pts = (const float*)d_in[1];
    float* out = (float*)d_out;
    float* ws  = (float*)d_ws;           // needs 8 * 32768 * 4 B = 1 MiB

    asd_min_kernel<<<2 * NCHUNK * NQB, THREADS, 0, stream>>>(real_pts, pred_pts, ws);
    asd_reduce_kernel<<<1, 1024, 0, stream>>>(ws, out);
}

// Round 2
// 58.734 us; speedup vs baseline: 1.6339x; 1.6339x over previous
//
#include <hip/hip_runtime.h>
#include <math.h>

// ASD between two 16384x3 fp32 point sets. fp32-VALU compute-bound (no fp32
// MFMA on CDNA4; bf16 numerically insufficient at coords~128).
//
// R1 lesson: at QPT=2 the kernel was LDS-pipe-bound (one broadcast
// ds_read_b128 ~10-12 cyc per CU-pipe per 128 pairs; 8 waves/CU x 12 cyc
// > 40 cyc VALU). Fix: QPT=8 (one ds_read serves 512 pairs) and fold the
// -2 into pre-scaled query registers, seeding the fma chain with r^2:
//   t = fma(qz2,rz, fma(qy2,ry, fma(qx2,rx, r2)))  -> 3 fma + 1 fmin / pair.
// VALU floor: 536.9M pairs * 4 ops / 64 lanes * 2 cyc / 1024 SIMD = 27 us.
//
// Cross-chunk min via global atomicMin on uint bit patterns of clamped d2
// (non-negative fp32 is uint-order-isomorphic). ws = 32768 uints, memset to
// 0x7F7F7F7F (3.39e38) each launch.

#define NPTS    16384
#define THREADS 256
#define QPT     8                    // queries per thread
#define QBLK    (THREADS * QPT)      // 2048 queries per block
#define NQB     (NPTS / QBLK)        // 8 query-blocks per direction
#define NCHUNK  32
#define CHUNK   (NPTS / NCHUNK)      // 512 refs per chunk

__global__ __launch_bounds__(THREADS) void asd_min_kernel(
    const float* __restrict__ real_pts,
    const float* __restrict__ pred_pts,
    unsigned int* __restrict__ ws)
{
    const int bid   = blockIdx.x;          // 512 blocks: 2 dirs x 8 qb x 32 chunks
    const int dir   = bid >> 8;
    const int rem   = bid & 255;
    const int chunk = rem >> 3;            // 0..31
    const int qb    = rem & 7;             // 0..7

    // dir 0: pred -> real ; dir 1: real -> pred
    const float* __restrict__ qpts = dir ? real_pts : pred_pts;
    const float* __restrict__ rpts = dir ? pred_pts : real_pts;

    __shared__ float4 sref[CHUNK];         // {x,y,z,r2}: 8 KB

    const int tid = threadIdx.x;

    const int rbase = chunk * CHUNK;
    for (int i = tid; i < CHUNK; i += THREADS) {
        const float rx = rpts[(rbase + i) * 3 + 0];
        const float ry = rpts[(rbase + i) * 3 + 1];
        const float rz = rpts[(rbase + i) * 3 + 2];
        sref[i] = make_float4(rx, ry, rz, fmaf(rx, rx, fmaf(ry, ry, rz * rz)));
    }

    // Query registers: pre-scaled by -2 so the inner loop is pure fma.
    float qx2[QPT], qy2[QPT], qz2[QPT], q2[QPT], m[QPT];
    const int q0 = qb * QBLK + tid;
#pragma unroll
    for (int k = 0; k < QPT; ++k) {
        const int qi = q0 + k * THREADS;
        const float x = qpts[qi * 3 + 0];
        const float y = qpts[qi * 3 + 1];
        const float z = qpts[qi * 3 + 2];
        qx2[k] = -2.0f * x;
        qy2[k] = -2.0f * y;
        qz2[k] = -2.0f * z;
        q2[k]  = fmaf(x, x, fmaf(y, y, z * z));
        m[k]   = INFINITY;                 // min over r of (r2 - 2 q.r)
    }

    __syncthreads();

#pragma unroll 4
    for (int r = 0; r < CHUNK; ++r) {
        const float4 rv = sref[r];         // broadcast read: 1 per 512 pairs
#pragma unroll
        for (int k = 0; k < QPT; ++k) {
            float t = fmaf(qx2[k], rv.x, rv.w);
            t = fmaf(qy2[k], rv.y, t);
            t = fmaf(qz2[k], rv.z, t);
            m[k] = fminf(m[k], t);         // 3 fma + 1 min per pair
        }
    }

#pragma unroll
    for (int k = 0; k < QPT; ++k) {
        const int qi = q0 + k * THREADS;
        const float d2 = fmaxf(m[k] + q2[k], 0.0f);   // clamp (matches ref; also
                                                      // keeps uint-order valid)
        atomicMin(&ws[dir * NPTS + qi], __float_as_uint(d2));
    }
}

__global__ __launch_bounds__(1024) void asd_reduce_kernel(
    const unsigned int* __restrict__ ws, float* __restrict__ out)
{
    const int tid = threadIdx.x;
    float s = 0.0f;

    for (int q = tid; q < 2 * NPTS; q += 1024)
        s += sqrtf(__uint_as_float(ws[q]));

    __shared__ float red[16];
#pragma unroll
    for (int off = 32; off > 0; off >>= 1)
        s += __shfl_down(s, off, 64);
    const int wave = tid >> 6;
    const int lane = tid & 63;
    if (lane == 0) red[wave] = s;
    __syncthreads();
    if (tid < 16) {
        float v = red[tid];
#pragma unroll
        for (int off = 8; off > 0; off >>= 1)
            v += __shfl_down(v, off, 16);
        if (tid == 0) out[0] = v / (float)(2 * NPTS);
    }
}

extern "C" void kernel_launch(void* const* d_in, const int* in_sizes, int n_in,
                              void* d_out, int out_size, void* d_ws, size_t ws_size,
                              hipStream_t stream)
{
    const float* real_pts = (const float*)d_in[0];
    const float* pred_pts = (const float*)d_in[1];
    float* out = (float*)d_out;
    unsigned int* ws = (unsigned int*)d_ws;    // 2*16384 uints = 128 KiB

    // Init per-query running mins to a huge float (0x7F7F7F7F = 3.39e38).
    hipMemsetAsync(ws, 0x7F, 2 * NPTS * sizeof(unsigned int), stream);

    asd_min_kernel<<<2 * NQB * NCHUNK, THREADS, 0, stream>>>(real_pts, pred_pts, ws);
    asd_reduce_kernel<<<1, 1024, 0, stream>>>(ws, out);
}